// Round 20
// baseline (138.073 us; speedup 1.0000x reference)
//
#include <hip/hip_runtime.h>
#include <stdint.h>

typedef float    f32x4 __attribute__((ext_vector_type(4)));
typedef _Float16 f16x8 __attribute__((ext_vector_type(8)));
typedef _Float16 f16x4 __attribute__((ext_vector_type(4)));
typedef _Float16 f16x2 __attribute__((ext_vector_type(2)));

#define BSZ  32768
#define MHOP 8
#define DDIM 128
#define HDIM 512
#define BT   8        // batches per tile
#define ROWS 64       // BT*MHOP rows per tile
#define NT   16       // tiles per block
#define NBLK 256      // 1 block per CU
#define AQLD 136      // padded a_q row stride (f16); 272 B = 17*16
#define NW   16       // waves per block
#define COLW 32       // hidden cols per wave

// Relaxed barrier: LDS-visibility only; vmcnt loads stay in flight.
#define BAR_LDS() do { \
    asm volatile("s_waitcnt lgkmcnt(0)" ::: "memory"); \
    __builtin_amdgcn_s_barrier(); \
} while (0)

// Cross-lane on VALU (DPP) instead of the DS pipe.
#define DPP_ADD(s, ctrl) ((s) + __int_as_float(__builtin_amdgcn_update_dpp(0, __float_as_int(s), (ctrl), 0xF, 0xF, true)))
#define DPP_MAX(s, ctrl) fmaxf((s), __int_as_float(__builtin_amdgcn_update_dpp(0, __float_as_int(s), (ctrl), 0xF, 0xF, true)))
#define SWZ_ADD(s, pat)  ((s) + __int_as_float(__builtin_amdgcn_ds_swizzle(__float_as_int(s), (pat))))

// ---- prep A: W1 k-half -> W1k f16 row-major [512][128] ----
__global__ void prep_w1k(const float* __restrict__ W1, _Float16* __restrict__ W1k) {
    int i = (blockIdx.x * blockDim.x + threadIdx.x) * 4;   // over 512*128
    int h = i >> 7, c = i & 127;
    float4 v = *reinterpret_cast<const float4*>(W1 + (size_t)h * 256 + 128 + c);
    f16x4 o;
    o[0]=(_Float16)v.x; o[1]=(_Float16)v.y; o[2]=(_Float16)v.z; o[3]=(_Float16)v.w;
    *reinterpret_cast<f16x4*>(W1k + (size_t)h * 128 + c) = o;
}

// ---- prep B: W1 q-half -> packed MFMA B-fragments, 16 waves x 32 cols.
//      id = (w,kf,fc,l): w=id>>9, kf=(id>>7)&3, fc=(id>>6)&1, l=id&63 ;
//      h = w*32+fc*16+(l&15), k = kf*32+(l>>4)*8 ;
//      store at ((w*8 + kf*2 + fc)*64 + l)*8 ----
__global__ void prep_w1q_pack(const float* __restrict__ W1, _Float16* __restrict__ Pq) {
    int id = blockIdx.x * blockDim.x + threadIdx.x;   // 8192
    int l  = id & 63;
    int fc = (id >> 6) & 1;
    int kf = (id >> 7) & 3;
    int w  = id >> 9;
    int h  = w * COLW + fc * 16 + (l & 15);
    int k  = kf * 32 + (l >> 4) * 8;
    const float* s = W1 + (size_t)h * 256 + k;
    float4 a = *reinterpret_cast<const float4*>(s);
    float4 b = *reinterpret_cast<const float4*>(s + 4);
    f16x8 p;
    p[0]=(_Float16)a.x; p[1]=(_Float16)a.y; p[2]=(_Float16)a.z; p[3]=(_Float16)a.w;
    p[4]=(_Float16)b.x; p[5]=(_Float16)b.y; p[6]=(_Float16)b.z; p[7]=(_Float16)b.w;
    *reinterpret_cast<f16x8*>(Pq + (size_t)((w * 8 + kf * 2 + fc) * 64 + l) * 8) = p;
}

__device__ __forceinline__ f16x8 cvt_f16x8(float4 x0, float4 x1) {
    f16x8 p;
    p[0]=(_Float16)x0.x; p[1]=(_Float16)x0.y; p[2]=(_Float16)x0.z; p[3]=(_Float16)x0.w;
    p[4]=(_Float16)x1.x; p[5]=(_Float16)x1.y; p[6]=(_Float16)x1.z; p[7]=(_Float16)x1.w;
    return p;
}

// ---- fused kernel, 16 waves (4/SIMD): W1k in LDS (shared), W1q(32 cols) in regs,
//      DPP epilogue/softmax, relaxed barriers, 2 barriers/tile.
//      Single-arg launch_bounds: 1024-thread block forces 4 waves/SIMD min,
//      natural VGPR cap = 512/4 = 128 (no extra-block squeeze). ----
__global__ void __launch_bounds__(1024) fused_kernel(
    const float* __restrict__ q_vec,
    const float* __restrict__ k_vec,
    const float* __restrict__ v_vec,
    const _Float16* __restrict__ W1k,
    const _Float16* __restrict__ Pq,
    const float* __restrict__ W2,
    float* __restrict__ out)
{
    __shared__ __align__(16) _Float16 w1k_lds[HDIM * DDIM];  // 128 KB, swizzled
    __shared__ __align__(16) _Float16 a_k[ROWS * DDIM];      // 16 KB, swizzled
    __shared__ __align__(16) _Float16 a_q[BT * AQLD];        // 2.125 KB
    __shared__ __align__(16) _Float16 u_lds[HDIM * BT];      // 8 KB, [h][bb]
    __shared__ __align__(16) float scores_part[NW][ROWS];    // 4 KB
    // total ~158.1 KB -> 1 block/CU, 16 waves

    const int t  = threadIdx.x;
    const int w  = t >> 6;     // wave 0..15: hidden cols [32w, 32w+32)
    const int l  = t & 63;
    const int lg = l >> 4;
    const int ll = l & 15;
    const int vb_b   = w >> 1;            // batch this wave outputs
    const int vb_col = (w & 1) * 64 + l;  // d-column this lane outputs
    const long tile0 = (long)blockIdx.x * NT;

    // ---- stage W1k -> LDS once (1024 threads, 8 iters) ----
    #pragma unroll
    for (int i2 = 0; i2 < 8; ++i2) {
        int cid = i2 * 1024 + t;                 // 8192 chunks of 8
        int row = cid >> 4, c = cid & 15;
        f16x8 p = *reinterpret_cast<const f16x8*>(W1k + (size_t)cid * 8);
        *reinterpret_cast<f16x8*>(&w1k_lds[row * DDIM + ((c ^ (row & 7)) * 8)]) = p;
    }

    // ---- W1q slice for this wave: 8 frags = 32 VGPR ----
    f16x8 w1qf[4][2];
    {
        const _Float16* pqw = Pq + (size_t)(w * 8) * 512 + l * 8;
        #pragma unroll
        for (int kf = 0; kf < 4; ++kf)
            #pragma unroll
            for (int fc = 0; fc < 2; ++fc)
                w1qf[kf][fc] = *reinterpret_cast<const f16x8*>(
                    pqw + (size_t)(kf * 2 + fc) * 512);
    }
    float w2r[2];
    #pragma unroll
    for (int fc = 0; fc < 2; ++fc) w2r[fc] = W2[w * COLW + fc * 16 + ll];

    float4 kr[2]; float2 qr;

    // ---- prologue: prefetch tile 0 (k: 1 chunk/thread; q: t<512 float2) ----
    {
        const long b0p = tile0 * BT;
        const float4* ks = reinterpret_cast<const float4*>(k_vec + b0p * (MHOP * DDIM));
        kr[0] = ks[t * 2]; kr[1] = ks[t * 2 + 1];
        if (t < 512)
            qr = *reinterpret_cast<const float2*>(q_vec + (b0p + (t >> 6)) * DDIM + (t & 63) * 2);
    }

    for (int it = 0; it < NT; ++it) {
        const long b0 = (tile0 + it) * BT;

        // ---- stage current tile from prefetch regs ----
        {
            int row = t >> 4, c = t & 15;
            *reinterpret_cast<f16x8*>(&a_k[row * DDIM + ((c ^ (row & 7)) * 8)]) =
                cvt_f16x8(kr[0], kr[1]);
        }
        if (t < 512) {
            f16x2 qq; qq[0] = (_Float16)qr.x; qq[1] = (_Float16)qr.y;
            *reinterpret_cast<f16x2*>(&a_q[(t >> 6) * AQLD + (t & 63) * 2]) = qq;
        }
        BAR_LDS();   // bar1: a_k/a_q (and on it=0, w1k_lds) visible

        // ---- issue next tile's k/q loads + this tile's v loads ----
        if (it + 1 < NT) {
            const long bn = b0 + BT;
            const float4* ks = reinterpret_cast<const float4*>(k_vec + bn * (MHOP * DDIM));
            kr[0] = ks[t * 2]; kr[1] = ks[t * 2 + 1];
            if (t < 512)
                qr = *reinterpret_cast<const float2*>(q_vec + (bn + (t >> 6)) * DDIM + (t & 63) * 2);
        }
        float vr[8];
        {
            const float* vb = v_vec + (b0 + vb_b) * (MHOP * DDIM) + vb_col;
            #pragma unroll
            for (int m = 0; m < MHOP; ++m)
                vr[m] = vb[m * DDIM];
        }

        // ---- q-GEMM: u (8 rows x this wave's 32 cols), B from regs ----
        {
            f32x4 accu[2] = {};
            #pragma unroll
            for (int kf = 0; kf < 4; ++kf) {
                const int kk = kf * 32 + lg * 8;
                f16x8 aq = *reinterpret_cast<const f16x8*>(&a_q[(ll & 7) * AQLD + kk]);
                #pragma unroll
                for (int fc = 0; fc < 2; ++fc)
                    accu[fc] = __builtin_amdgcn_mfma_f32_16x16x32_f16(aq, w1qf[kf][fc], accu[fc], 0, 0, 0);
            }
            if (lg < 2) {
                #pragma unroll
                for (int fc = 0; fc < 2; ++fc) {
                    f16x4 up;
                    up[0]=(_Float16)accu[fc][0]; up[1]=(_Float16)accu[fc][1];
                    up[2]=(_Float16)accu[fc][2]; up[3]=(_Float16)accu[fc][3];
                    *reinterpret_cast<f16x4*>(&u_lds[(w * COLW + fc * 16 + ll) * BT + lg * 4]) = up;
                }
            }
        }
        // no barrier: wave reads back only its own u columns

        // ---- k-GEMM: 64 rows x 32 cols/wave, K=128, B from LDS ----
        f32x4 acc[4][2] = {};
        #pragma unroll
        for (int kf = 0; kf < 4; ++kf) {
            const int ch = kf * 4 + lg;
            f16x8 bf[2];
            #pragma unroll
            for (int fc = 0; fc < 2; ++fc) {
                int hrow = w * COLW + fc * 16 + ll;
                bf[fc] = *reinterpret_cast<const f16x8*>(
                    &w1k_lds[hrow * DDIM + ((ch ^ (hrow & 7)) * 8)]);
            }
            #pragma unroll
            for (int fr = 0; fr < 4; ++fr) {
                int row = fr * 16 + ll;
                f16x8 af = *reinterpret_cast<const f16x8*>(
                    &a_k[row * DDIM + ((ch ^ (row & 7)) * 8)]);
                #pragma unroll
                for (int fc = 0; fc < 2; ++fc)
                    acc[fr][fc] = __builtin_amdgcn_mfma_f32_16x16x32_f16(af, bf[fc], acc[fr][fc], 0, 0, 0);
            }
        }

        // ---- u reads: 2 x ds_read_b128 + cndmask extract ----
        float uf[4][2];
        #pragma unroll
        for (int fc = 0; fc < 2; ++fc) {
            f16x8 urow = *reinterpret_cast<const f16x8*>(
                &u_lds[(w * COLW + fc * 16 + ll) * BT]);
            #pragma unroll
            for (int fr = 0; fr < 4; ++fr) {
                float lo = (float)urow[fr * 2];
                float hi = (float)urow[fr * 2 + 1];
                uf[fr][fc] = (lg & 2) ? hi : lo;   // bb = fr*2 + (lg>>1)
            }
        }

        // ---- epilogue: s(row) = sum_h W2[h]*relu(t+u); 16-lane DPP reduce ----
        #pragma unroll
        for (int fr = 0; fr < 4; ++fr) {
            float sj[4];
            #pragma unroll
            for (int j = 0; j < 4; ++j) {
                float s = 0.f;
                #pragma unroll
                for (int fc = 0; fc < 2; ++fc)
                    s += w2r[fc] * fmaxf(acc[fr][fc][j] + uf[fr][fc], 0.f);
                s = DPP_ADD(s, 0xB1);    // xor1
                s = DPP_ADD(s, 0x4E);    // xor2
                s = DPP_ADD(s, 0x141);   // xor4 (row_half_mirror)
                s = DPP_ADD(s, 0x140);   // xor8 (row_mirror)
                sj[j] = s;
            }
            if (ll == 0) {
                f32x4 sv; sv[0]=sj[0]; sv[1]=sj[1]; sv[2]=sj[2]; sv[3]=sj[3];
                *reinterpret_cast<f32x4*>(&scores_part[w][fr * 16 + lg * 4]) = sv;
            }
        }
        BAR_LDS();   // bar2: scores_part visible; prefetch loads stay in flight

        // ---- wave-redundant softmax for batch vb_b (16 partials, 2 reads) ----
        float attn;
        {
            const int m = l & 7, g = l >> 3;   // g in 0..7 indexes partial pairs
            const int row = vb_b * 8 + m;
            float s = scores_part[2 * g][row] + scores_part[2 * g + 1][row];
            s = SWZ_ADD(s, 0x201F);          // xor8  (combines g^1)
            s = SWZ_ADD(s, 0x401F);          // xor16 (combines g^2)
            s += __shfl_xor(s, 32);          // xor32 (combines g^4)
            float mx = s;
            mx = DPP_MAX(mx, 0xB1);
            mx = DPP_MAX(mx, 0x4E);
            mx = DPP_MAX(mx, 0x141);
            float e = __expf(s - mx);
            float sum = e;
            sum = DPP_ADD(sum, 0xB1);
            sum = DPP_ADD(sum, 0x4E);
            sum = DPP_ADD(sum, 0x141);
            attn = e / sum;                  // lane l holds attn(l&7) for vb_b
        }

        // ---- output: out[vb_b][vb_col] = sum_m attn(m)*v[m] ----
        {
            float a0 = 0.f;
            #pragma unroll
            for (int m = 0; m < MHOP; ++m) {
                float at = __shfl(attn, m, 8);
                a0 += at * vr[m];
            }
            out[(b0 + vb_b) * DDIM + vb_col] = a0;
        }
    }
}

extern "C" void kernel_launch(void* const* d_in, const int* in_sizes, int n_in,
                              void* d_out, int out_size, void* d_ws, size_t ws_size,
                              hipStream_t stream) {
    const float* q  = (const float*)d_in[0];
    const float* k  = (const float*)d_in[1];
    const float* v  = (const float*)d_in[2];
    const float* W1 = (const float*)d_in[3];
    const float* W2 = (const float*)d_in[4];

    _Float16* W1k = (_Float16*)d_ws;                       // 128 KB
    _Float16* Pq  = (_Float16*)((char*)d_ws + 128 * 1024); // 128 KB

    prep_w1k<<<(HDIM * DDIM) / (256 * 4), 256, 0, stream>>>(W1, W1k);
    prep_w1q_pack<<<8192 / 256, 256, 0, stream>>>(W1, Pq);
    fused_kernel<<<NBLK, 1024, 0, stream>>>(q, k, v, W1k, Pq, W2, (float*)d_out);
}

// Round 21
// 114.977 us; speedup vs baseline: 1.2009x; 1.2009x over previous
//
#include <hip/hip_runtime.h>
#include <stdint.h>

typedef float    f32x4 __attribute__((ext_vector_type(4)));
typedef _Float16 f16x8 __attribute__((ext_vector_type(8)));
typedef _Float16 f16x4 __attribute__((ext_vector_type(4)));

#define BSZ  32768
#define MHOP 8
#define DDIM 128
#define HDIM 512
#define BT   8        // batches per tile
#define ROWS 64       // BT*MHOP rows per tile
#define NT   16       // tiles per block
#define NBLK 256      // 1 block per CU
#define AQLD 136      // padded a_q row stride (f16)

// Relaxed barrier: LDS-visibility only; vmcnt loads stay in flight.
#define BAR_LDS() do { \
    asm volatile("s_waitcnt lgkmcnt(0)" ::: "memory"); \
    __builtin_amdgcn_s_barrier(); \
} while (0)

// Cross-lane on VALU (DPP) instead of the DS pipe.
#define DPP_ADD(s, ctrl) ((s) + __int_as_float(__builtin_amdgcn_update_dpp(0, __float_as_int(s), (ctrl), 0xF, 0xF, true)))
#define DPP_MAX(s, ctrl) fmaxf((s), __int_as_float(__builtin_amdgcn_update_dpp(0, __float_as_int(s), (ctrl), 0xF, 0xF, true)))
#define SWZ_ADD(s, pat)  ((s) + __int_as_float(__builtin_amdgcn_ds_swizzle(__float_as_int(s), (pat))))

// ---- prep A: W1 k-half -> W1k f16 row-major [512][128] ----
__global__ void prep_w1k(const float* __restrict__ W1, _Float16* __restrict__ W1k) {
    int i = (blockIdx.x * blockDim.x + threadIdx.x) * 4;   // over 512*128
    int h = i >> 7, c = i & 127;
    float4 v = *reinterpret_cast<const float4*>(W1 + (size_t)h * 256 + 128 + c);
    f16x4 o;
    o[0]=(_Float16)v.x; o[1]=(_Float16)v.y; o[2]=(_Float16)v.z; o[3]=(_Float16)v.w;
    *reinterpret_cast<f16x4*>(W1k + (size_t)h * 128 + c) = o;
}

// ---- prep B: W1 q-half -> packed MFMA B-fragments (8 waves x 64 cols).
//      id = (w,kf,fc,l): w=id>>10, kf=(id>>8)&3, fc=(id>>6)&3, l=id&63 ;
//      h = w*64+fc*16+(l&15), k = kf*32+(l>>4)*8  (r10-verified layout) ----
__global__ void prep_w1q_pack(const float* __restrict__ W1, _Float16* __restrict__ Pq) {
    int id = blockIdx.x * blockDim.x + threadIdx.x;   // 8192
    int l  = id & 63;
    int fc = (id >> 6) & 3;
    int kf = (id >> 8) & 3;
    int w  = id >> 10;
    int h  = w * 64 + fc * 16 + (l & 15);
    int k  = kf * 32 + (l >> 4) * 8;
    const float* s = W1 + (size_t)h * 256 + k;
    float4 a = *reinterpret_cast<const float4*>(s);
    float4 b = *reinterpret_cast<const float4*>(s + 4);
    f16x8 p;
    p[0]=(_Float16)a.x; p[1]=(_Float16)a.y; p[2]=(_Float16)a.z; p[3]=(_Float16)a.w;
    p[4]=(_Float16)b.x; p[5]=(_Float16)b.y; p[6]=(_Float16)b.z; p[7]=(_Float16)b.w;
    *reinterpret_cast<f16x8*>(Pq + (size_t)id * 8) = p;
}

__device__ __forceinline__ f16x8 cvt_f16x8(float4 x0, float4 x1) {
    f16x8 p;
    p[0]=(_Float16)x0.x; p[1]=(_Float16)x0.y; p[2]=(_Float16)x0.z; p[3]=(_Float16)x0.w;
    p[4]=(_Float16)x1.x; p[5]=(_Float16)x1.y; p[6]=(_Float16)x1.z; p[7]=(_Float16)x1.w;
    return p;
}

// ---- fused kernel (r14 base): W1k in LDS; q-GEMM B streamed from packed L2
//      (frees 64 VGPR so kr/qr prefetch stays hoisted); DPP epilogue/softmax ----
__global__ void __launch_bounds__(512, 2) fused_kernel(
    const float* __restrict__ q_vec,
    const float* __restrict__ k_vec,
    const float* __restrict__ v_vec,
    const _Float16* __restrict__ W1k,
    const _Float16* __restrict__ Pq,
    const float* __restrict__ W2,
    float* __restrict__ out)
{
    __shared__ __align__(16) _Float16 w1k_lds[HDIM * DDIM];  // 128 KB, swizzled
    __shared__ __align__(16) _Float16 a_k[ROWS * DDIM];      // 16 KB, swizzled
    __shared__ __align__(16) _Float16 a_q[BT * AQLD];        // 2.125 KB
    __shared__ __align__(16) _Float16 u_lds[HDIM * BT];      // 8 KB, [h][bb]
    __shared__ __align__(16) float scores_part[8][ROWS];     // 2 KB
    // total ~156.1 KB -> 1 block/CU

    const int t  = threadIdx.x;
    const int w  = t >> 6;     // wave 0..7: hidden cols [64w,64w+64), batch w for V
    const int l  = t & 63;
    const int lg = l >> 4;
    const int ll = l & 15;
    const long tile0 = (long)blockIdx.x * NT;

    // ---- stage W1k -> LDS once ----
    #pragma unroll
    for (int i2 = 0; i2 < 16; ++i2) {
        int cid = i2 * 512 + t;
        int row = cid >> 4, c = cid & 15;
        f16x8 p = *reinterpret_cast<const f16x8*>(W1k + (size_t)cid * 8);
        *reinterpret_cast<f16x8*>(&w1k_lds[row * DDIM + ((c ^ (row & 7)) * 8)]) = p;
    }

    float w2r[4];
    #pragma unroll
    for (int fc = 0; fc < 4; ++fc) w2r[fc] = W2[w * 64 + fc * 16 + ll];

    // per-wave packed W1q fragment stream (L2-resident, 16 reads/tile)
    const _Float16* pqw = Pq + (size_t)(w * 16) * 512 + l * 8;

    // ---- prologue: prefetch tile 0 ----
    float4 kr[2][2]; float4 qr[2];
    {
        const long b0p = tile0 * BT;
        const float4* ks = reinterpret_cast<const float4*>(k_vec + b0p * (MHOP * DDIM));
        kr[0][0] = ks[t * 2];         kr[0][1] = ks[t * 2 + 1];
        kr[1][0] = ks[(t + 512) * 2]; kr[1][1] = ks[(t + 512) * 2 + 1];
        if (t < 128) {
            const float4* qs = reinterpret_cast<const float4*>(q_vec + b0p * DDIM);
            qr[0] = qs[t * 2]; qr[1] = qs[t * 2 + 1];
        }
    }

    for (int it = 0; it < NT; ++it) {
        const long b0 = tile0 * BT + (long)it * BT;

        // ---- stage current tile ----
        #pragma unroll
        for (int cc = 0; cc < 2; ++cc) {
            int cid = t + cc * 512, row = cid >> 4, c = cid & 15;
            *reinterpret_cast<f16x8*>(&a_k[row * DDIM + ((c ^ (row & 7)) * 8)]) =
                cvt_f16x8(kr[cc][0], kr[cc][1]);
        }
        if (t < 128) {
            int row = t >> 4, c = t & 15;
            *reinterpret_cast<f16x8*>(&a_q[row * AQLD + c * 8]) = cvt_f16x8(qr[0], qr[1]);
        }
        BAR_LDS();   // bar1

        // ---- issue next tile's k/q loads (kr regs now free to stay early) ----
        if (it + 1 < NT) {
            const long bn = b0 + BT;
            const float4* ks = reinterpret_cast<const float4*>(k_vec + bn * (MHOP * DDIM));
            kr[0][0] = ks[t * 2];         kr[0][1] = ks[t * 2 + 1];
            kr[1][0] = ks[(t + 512) * 2]; kr[1][1] = ks[(t + 512) * 2 + 1];
            if (t < 128) {
                const float4* qs = reinterpret_cast<const float4*>(q_vec + bn * DDIM);
                qr[0] = qs[t * 2]; qr[1] = qs[t * 2 + 1];
            }
        }

        // ---- q-GEMM: u (8 rows x 64 cols), B streamed from Pq (transient) ----
        {
            f32x4 accu[4] = {};
            #pragma unroll
            for (int kf = 0; kf < 4; ++kf) {
                const int kk = kf * 32 + lg * 8;
                f16x8 aq = *reinterpret_cast<const f16x8*>(&a_q[(ll & 7) * AQLD + kk]);
                const _Float16* pq_kf = pqw + (size_t)(kf * 4) * 512;
                #pragma unroll
                for (int fc = 0; fc < 4; ++fc) {
                    f16x8 bq = *reinterpret_cast<const f16x8*>(pq_kf + (size_t)fc * 512);
                    accu[fc] = __builtin_amdgcn_mfma_f32_16x16x32_f16(aq, bq, accu[fc], 0, 0, 0);
                }
            }
            if (lg < 2) {
                #pragma unroll
                for (int fc = 0; fc < 4; ++fc) {
                    f16x4 up;
                    up[0]=(_Float16)accu[fc][0]; up[1]=(_Float16)accu[fc][1];
                    up[2]=(_Float16)accu[fc][2]; up[3]=(_Float16)accu[fc][3];
                    *reinterpret_cast<f16x4*>(&u_lds[(w * 64 + fc * 16 + ll) * BT + lg * 4]) = up;
                }
            }
        }
        // no barrier: wave reads back only its own u columns

        // ---- k-GEMM: 64 rows x 64 cols/wave, K=128, B from LDS ----
        f32x4 acc[4][4] = {};
        #pragma unroll
        for (int kf = 0; kf < 4; ++kf) {
            const int ch = kf * 4 + lg;
            f16x8 bf[4];
            #pragma unroll
            for (int fc = 0; fc < 4; ++fc) {
                int hrow = w * 64 + fc * 16 + ll;
                bf[fc] = *reinterpret_cast<const f16x8*>(
                    &w1k_lds[hrow * DDIM + ((ch ^ (hrow & 7)) * 8)]);
            }
            #pragma unroll
            for (int fr = 0; fr < 4; ++fr) {
                int row = fr * 16 + ll;
                f16x8 af = *reinterpret_cast<const f16x8*>(
                    &a_k[row * DDIM + ((ch ^ (row & 7)) * 8)]);
                #pragma unroll
                for (int fc = 0; fc < 4; ++fc)
                    acc[fr][fc] = __builtin_amdgcn_mfma_f32_16x16x32_f16(af, bf[fc], acc[fr][fc], 0, 0, 0);
            }
        }

        // ---- u reads: 4 x ds_read_b128 + cndmask extract ----
        float uf[4][4];
        #pragma unroll
        for (int fc = 0; fc < 4; ++fc) {
            f16x8 urow = *reinterpret_cast<const f16x8*>(
                &u_lds[(w * 64 + fc * 16 + ll) * BT]);
            #pragma unroll
            for (int fr = 0; fr < 4; ++fr) {
                float lo = (float)urow[fr * 2];
                float hi = (float)urow[fr * 2 + 1];
                uf[fr][fc] = (lg & 2) ? hi : lo;   // bb = fr*2 + (lg>>1)
            }
        }

        // ---- epilogue: s(row) = sum_h W2[h]*relu(t+u); 16-lane DPP reduce ----
        #pragma unroll
        for (int fr = 0; fr < 4; ++fr) {
            float sj[4];
            #pragma unroll
            for (int j = 0; j < 4; ++j) {
                float s = 0.f;
                #pragma unroll
                for (int fc = 0; fc < 4; ++fc)
                    s += w2r[fc] * fmaxf(acc[fr][fc][j] + uf[fr][fc], 0.f);
                s = DPP_ADD(s, 0xB1);    // xor1
                s = DPP_ADD(s, 0x4E);    // xor2
                s = DPP_ADD(s, 0x141);   // xor4 (row_half_mirror)
                s = DPP_ADD(s, 0x140);   // xor8 (row_mirror)
                sj[j] = s;
            }
            if (ll == 0) {
                f32x4 sv; sv[0]=sj[0]; sv[1]=sj[1]; sv[2]=sj[2]; sv[3]=sj[3];
                *reinterpret_cast<f32x4*>(&scores_part[w][fr * 16 + lg * 4]) = sv;
            }
        }

        // ---- this tile's v loads (issued post-epilogue: acc mostly dead) ----
        float2 vr[8];
        {
            const float* vb = v_vec + (b0 + w) * (MHOP * DDIM) + l * 2;
            #pragma unroll
            for (int m = 0; m < MHOP; ++m)
                vr[m] = *reinterpret_cast<const float2*>(vb + m * DDIM);
        }
        BAR_LDS();   // bar2: scores_part visible; prefetch loads stay in flight

        // ---- wave-redundant softmax for batch w ----
        float attn;
        {
            const int m = l & 7, g = l >> 3;
            float s = scores_part[g][w * 8 + m];
            s = SWZ_ADD(s, 0x201F);          // xor8
            s = SWZ_ADD(s, 0x401F);          // xor16
            s += __shfl_xor(s, 32);          // xor32
            float mx = s;
            mx = DPP_MAX(mx, 0xB1);
            mx = DPP_MAX(mx, 0x4E);
            mx = DPP_MAX(mx, 0x141);
            float e = __expf(s - mx);
            float sum = e;
            sum = DPP_ADD(sum, 0xB1);
            sum = DPP_ADD(sum, 0x4E);
            sum = DPP_ADD(sum, 0x141);
            attn = e / sum;                  // lane l holds attn(l&7) for batch w
        }

        // ---- output: out[w][2l..2l+1] = sum_m attn(m)*v[m] ----
        {
            float a0 = 0.f, a1 = 0.f;
            #pragma unroll
            for (int m = 0; m < MHOP; ++m) {
                float at = __shfl(attn, m, 8);
                a0 += at * vr[m].x;
                a1 += at * vr[m].y;
            }
            float2 o; o.x = a0; o.y = a1;
            *reinterpret_cast<float2*>(out + (b0 + w) * DDIM + l * 2) = o;
        }
    }
}

extern "C" void kernel_launch(void* const* d_in, const int* in_sizes, int n_in,
                              void* d_out, int out_size, void* d_ws, size_t ws_size,
                              hipStream_t stream) {
    const float* q  = (const float*)d_in[0];
    const float* k  = (const float*)d_in[1];
    const float* v  = (const float*)d_in[2];
    const float* W1 = (const float*)d_in[3];
    const float* W2 = (const float*)d_in[4];

    _Float16* W1k = (_Float16*)d_ws;                       // 128 KB
    _Float16* Pq  = (_Float16*)((char*)d_ws + 128 * 1024); // 128 KB

    prep_w1k<<<(HDIM * DDIM) / (256 * 4), 256, 0, stream>>>(W1, W1k);
    prep_w1q_pack<<<8192 / 256, 256, 0, stream>>>(W1, Pq);
    fused_kernel<<<NBLK, 512, 0, stream>>>(q, k, v, W1k, Pq, W2, (float*)d_out);
}

// Round 22
// 81.012 us; speedup vs baseline: 1.7044x; 1.4193x over previous
//
#include <hip/hip_runtime.h>
#include <stdint.h>

typedef float    f32x4 __attribute__((ext_vector_type(4)));
typedef _Float16 f16x8 __attribute__((ext_vector_type(8)));
typedef _Float16 f16x4 __attribute__((ext_vector_type(4)));

#define BSZ  32768
#define MHOP 8
#define DDIM 128
#define HDIM 512
#define BT   8        // batches per tile
#define ROWS 64       // BT*MHOP rows per tile
#define NT   16       // tiles per block
#define NBLK 256      // 1 block per CU
#define AQLD 136      // padded a_q row stride (f16)

// Relaxed barrier: LDS-visibility only; vmcnt loads stay in flight.
#define BAR_LDS() do { \
    asm volatile("s_waitcnt lgkmcnt(0)" ::: "memory"); \
    __builtin_amdgcn_s_barrier(); \
} while (0)

// Cross-lane on VALU (DPP) instead of the DS pipe.
#define DPP_ADD(s, ctrl) ((s) + __int_as_float(__builtin_amdgcn_update_dpp(0, __float_as_int(s), (ctrl), 0xF, 0xF, true)))
#define DPP_MAX(s, ctrl) fmaxf((s), __int_as_float(__builtin_amdgcn_update_dpp(0, __float_as_int(s), (ctrl), 0xF, 0xF, true)))
#define SWZ_ADD(s, pat)  ((s) + __int_as_float(__builtin_amdgcn_ds_swizzle(__float_as_int(s), (pat))))

// ---- prep: split W1 [512][256] f32 into W1q/W1k [512][128] f16 ----
__global__ void prep_w1(const float* __restrict__ W1,
                        _Float16* __restrict__ W1q, _Float16* __restrict__ W1k) {
    int i = (blockIdx.x * blockDim.x + threadIdx.x) * 4;   // over 512*256
    float4 v = *reinterpret_cast<const float4*>(W1 + i);
    f16x4 o;
    o[0]=(_Float16)v.x; o[1]=(_Float16)v.y; o[2]=(_Float16)v.z; o[3]=(_Float16)v.w;
    int h = i >> 8, c = i & 255;
    _Float16* dst = (c < 128) ? (W1q + h * 128 + c) : (W1k + h * 128 + (c - 128));
    *reinterpret_cast<f16x4*>(dst) = o;
}

__device__ __forceinline__ f16x8 cvt_f16x8(float4 x0, float4 x1) {
    f16x8 p;
    p[0]=(_Float16)x0.x; p[1]=(_Float16)x0.y; p[2]=(_Float16)x0.z; p[3]=(_Float16)x0.w;
    p[4]=(_Float16)x1.x; p[5]=(_Float16)x1.y; p[6]=(_Float16)x1.z; p[7]=(_Float16)x1.w;
    return p;
}

// ---- fused persistent kernel: W1k in LDS, W1q in regs; DPP epilogue/softmax ----
__global__ void __launch_bounds__(512, 2) fused_kernel(
    const float* __restrict__ q_vec,
    const float* __restrict__ k_vec,
    const float* __restrict__ v_vec,
    const _Float16* __restrict__ W1q,
    const _Float16* __restrict__ W1k,
    const float* __restrict__ W2,
    float* __restrict__ out)
{
    __shared__ __align__(16) _Float16 w1k_lds[HDIM * DDIM];  // 128 KB, swizzled
    __shared__ __align__(16) _Float16 a_k[ROWS * DDIM];      // 16 KB, swizzled
    __shared__ __align__(16) _Float16 a_q[BT * AQLD];        // 2.125 KB
    __shared__ __align__(16) _Float16 u_lds[HDIM * BT];      // 8 KB, [h][bb]
    __shared__ __align__(16) float scores_part[8][ROWS];     // 2 KB
    // total ~156.1 KB -> 1 block/CU

    const int t  = threadIdx.x;
    const int w  = t >> 6;     // wave 0..7: hidden cols [64w,64w+64), batch w for V
    const int l  = t & 63;
    const int lg = l >> 4;
    const int ll = l & 15;
    const long tile0 = (long)blockIdx.x * NT;

    // ---- stage W1k -> LDS once ----
    #pragma unroll
    for (int i2 = 0; i2 < 16; ++i2) {
        int cid = i2 * 512 + t;
        int row = cid >> 4, c = cid & 15;
        f16x8 p = *reinterpret_cast<const f16x8*>(W1k + (size_t)cid * 8);
        *reinterpret_cast<f16x8*>(&w1k_lds[row * DDIM + ((c ^ (row & 7)) * 8)]) = p;
    }

    // ---- W1q slice for this wave: 16 frags = 64 VGPR ----
    f16x8 w1qf[4][4];
    {
        const _Float16* base = W1q + (size_t)(w * 64 + ll) * DDIM + lg * 8;
        #pragma unroll
        for (int kf = 0; kf < 4; ++kf)
            #pragma unroll
            for (int fc = 0; fc < 4; ++fc)
                w1qf[kf][fc] = *reinterpret_cast<const f16x8*>(
                    base + (size_t)(fc * 16) * DDIM + kf * 32);
    }
    float w2r[4];
    #pragma unroll
    for (int fc = 0; fc < 4; ++fc) w2r[fc] = W2[w * 64 + fc * 16 + ll];

    // ---- prologue: prefetch tile 0 ----
    float4 kr[2][2]; float4 qr[2];
    {
        const long b0p = tile0 * BT;
        const float4* ks = reinterpret_cast<const float4*>(k_vec + b0p * (MHOP * DDIM));
        kr[0][0] = ks[t * 2];         kr[0][1] = ks[t * 2 + 1];
        kr[1][0] = ks[(t + 512) * 2]; kr[1][1] = ks[(t + 512) * 2 + 1];
        if (t < 128) {
            const float4* qs = reinterpret_cast<const float4*>(q_vec + b0p * DDIM);
            qr[0] = qs[t * 2]; qr[1] = qs[t * 2 + 1];
        }
    }

    for (int it = 0; it < NT; ++it) {
        const long b0 = tile0 * BT + (long)it * BT;

        // ---- stage current tile ----
        #pragma unroll
        for (int cc = 0; cc < 2; ++cc) {
            int cid = t + cc * 512, row = cid >> 4, c = cid & 15;
            *reinterpret_cast<f16x8*>(&a_k[row * DDIM + ((c ^ (row & 7)) * 8)]) =
                cvt_f16x8(kr[cc][0], kr[cc][1]);
        }
        if (t < 128) {
            int row = t >> 4, c = t & 15;
            *reinterpret_cast<f16x8*>(&a_q[row * AQLD + c * 8]) = cvt_f16x8(qr[0], qr[1]);
        }
        BAR_LDS();   // bar1

        // ---- issue next tile's k/q + this tile's v ----
        if (it + 1 < NT) {
            const long bn = b0 + BT;
            const float4* ks = reinterpret_cast<const float4*>(k_vec + bn * (MHOP * DDIM));
            kr[0][0] = ks[t * 2];         kr[0][1] = ks[t * 2 + 1];
            kr[1][0] = ks[(t + 512) * 2]; kr[1][1] = ks[(t + 512) * 2 + 1];
            if (t < 128) {
                const float4* qs = reinterpret_cast<const float4*>(q_vec + bn * DDIM);
                qr[0] = qs[t * 2]; qr[1] = qs[t * 2 + 1];
            }
        }
        float2 vr[8];
        {
            const float* vb = v_vec + (b0 + w) * (MHOP * DDIM) + l * 2;
            #pragma unroll
            for (int m = 0; m < MHOP; ++m)
                vr[m] = *reinterpret_cast<const float2*>(vb + m * DDIM);
        }

        // ---- q-GEMM: u (8 rows x 64 cols), B from regs; u packed [h][bb] ----
        {
            f32x4 accu[4] = {};
            #pragma unroll
            for (int kf = 0; kf < 4; ++kf) {
                const int kk = kf * 32 + lg * 8;
                f16x8 aq = *reinterpret_cast<const f16x8*>(&a_q[(ll & 7) * AQLD + kk]);
                #pragma unroll
                for (int fc = 0; fc < 4; ++fc)
                    accu[fc] = __builtin_amdgcn_mfma_f32_16x16x32_f16(aq, w1qf[kf][fc], accu[fc], 0, 0, 0);
            }
            if (lg < 2) {
                #pragma unroll
                for (int fc = 0; fc < 4; ++fc) {
                    f16x4 up;
                    up[0]=(_Float16)accu[fc][0]; up[1]=(_Float16)accu[fc][1];
                    up[2]=(_Float16)accu[fc][2]; up[3]=(_Float16)accu[fc][3];
                    *reinterpret_cast<f16x4*>(&u_lds[(w * 64 + fc * 16 + ll) * BT + lg * 4]) = up;
                }
            }
        }
        // no barrier: wave reads back only its own u columns

        // ---- k-GEMM: 64 rows x 64 cols/wave, K=128, B from LDS ----
        f32x4 acc[4][4] = {};
        #pragma unroll
        for (int kf = 0; kf < 4; ++kf) {
            const int ch = kf * 4 + lg;
            f16x8 bf[4];
            #pragma unroll
            for (int fc = 0; fc < 4; ++fc) {
                int hrow = w * 64 + fc * 16 + ll;
                bf[fc] = *reinterpret_cast<const f16x8*>(
                    &w1k_lds[hrow * DDIM + ((ch ^ (hrow & 7)) * 8)]);
            }
            #pragma unroll
            for (int fr = 0; fr < 4; ++fr) {
                int row = fr * 16 + ll;
                f16x8 af = *reinterpret_cast<const f16x8*>(
                    &a_k[row * DDIM + ((ch ^ (row & 7)) * 8)]);
                #pragma unroll
                for (int fc = 0; fc < 4; ++fc)
                    acc[fr][fc] = __builtin_amdgcn_mfma_f32_16x16x32_f16(af, bf[fc], acc[fr][fc], 0, 0, 0);
            }
        }

        // ---- u reads: 4 x ds_read_b128 (u[h][0..7]) + cndmask extract ----
        float uf[4][4];
        {
            #pragma unroll
            for (int fc = 0; fc < 4; ++fc) {
                f16x8 urow = *reinterpret_cast<const f16x8*>(
                    &u_lds[(w * 64 + fc * 16 + ll) * BT]);
                #pragma unroll
                for (int fr = 0; fr < 4; ++fr) {
                    float lo = (float)urow[fr * 2];
                    float hi = (float)urow[fr * 2 + 1];
                    uf[fr][fc] = (lg & 2) ? hi : lo;   // bb = fr*2 + (lg>>1)
                }
            }
        }

        // ---- epilogue: s(row) = sum_h W2[h]*relu(t+u); 16-lane reduce on DPP ----
        #pragma unroll
        for (int fr = 0; fr < 4; ++fr) {
            float sj[4];
            #pragma unroll
            for (int j = 0; j < 4; ++j) {
                float s = 0.f;
                #pragma unroll
                for (int fc = 0; fc < 4; ++fc)
                    s += w2r[fc] * fmaxf(acc[fr][fc][j] + uf[fr][fc], 0.f);
                s = DPP_ADD(s, 0xB1);    // xor1
                s = DPP_ADD(s, 0x4E);    // xor2
                s = DPP_ADD(s, 0x141);   // xor4 (row_half_mirror)
                s = DPP_ADD(s, 0x140);   // xor8 (row_mirror)
                sj[j] = s;               // all 16 lanes of this lg hold the sum
            }
            if (ll == 0) {
                f32x4 sv; sv[0]=sj[0]; sv[1]=sj[1]; sv[2]=sj[2]; sv[3]=sj[3];
                *reinterpret_cast<f32x4*>(&scores_part[w][fr * 16 + lg * 4]) = sv;
            }
        }
        BAR_LDS();   // bar2: scores_part visible

        // ---- wave-redundant softmax for batch w (DS-light) ----
        float attn;
        {
            const int m = l & 7, g = l >> 3;
            float s = scores_part[g][w * 8 + m];
            s = SWZ_ADD(s, 0x201F);          // xor8 (exact, within 32)
            s = SWZ_ADD(s, 0x401F);          // xor16
            s += __shfl_xor(s, 32);          // xor32
            // all lanes now hold s(l&7)
            float mx = s;
            mx = DPP_MAX(mx, 0xB1);
            mx = DPP_MAX(mx, 0x4E);
            mx = DPP_MAX(mx, 0x141);         // max over the 8-group
            float e = __expf(s - mx);
            float sum = e;
            sum = DPP_ADD(sum, 0xB1);
            sum = DPP_ADD(sum, 0x4E);
            sum = DPP_ADD(sum, 0x141);       // sum over the 8-group
            attn = e / sum;                  // lane l holds attn(l&7) for batch w
        }

        // ---- output: out[w][2l..2l+1] = sum_m attn(m)*v[m] ----
        {
            float a0 = 0.f, a1 = 0.f;
            #pragma unroll
            for (int m = 0; m < MHOP; ++m) {
                float at = __shfl(attn, m, 8);
                a0 += at * vr[m].x;
                a1 += at * vr[m].y;
            }
            float2 o; o.x = a0; o.y = a1;
            *reinterpret_cast<float2*>(out + (b0 + w) * DDIM + l * 2) = o;
        }
    }
}

extern "C" void kernel_launch(void* const* d_in, const int* in_sizes, int n_in,
                              void* d_out, int out_size, void* d_ws, size_t ws_size,
                              hipStream_t stream) {
    const float* q  = (const float*)d_in[0];
    const float* k  = (const float*)d_in[1];
    const float* v  = (const float*)d_in[2];
    const float* W1 = (const float*)d_in[3];
    const float* W2 = (const float*)d_in[4];

    _Float16* W1q = (_Float16*)d_ws;                       // 128 KB
    _Float16* W1k = (_Float16*)((char*)d_ws + 128 * 1024); // 128 KB

    prep_w1<<<(HDIM * 256) / (256 * 4), 256, 0, stream>>>(W1, W1q, W1k);
    fused_kernel<<<NBLK, 512, 0, stream>>>(q, k, v, W1q, W1k, W2, (float*)d_out);
}